// Round 5
// baseline (1299.548 us; speedup 1.0000x reference)
//
#include <hip/hip_runtime.h>
#include <math.h>

// Problem constants (reference: B,T,D=16,512,256; HS=512, D_A=64, R=8)
#define BB 16
#define TT 512
#define DD 256
#define HS 512
#define DA 64
#define RR 8
#define G4H 2048   // 4*HS

// -------- workspace layout (float offsets) --------
// s     :        0  (B*T*R =  65536)  <- k5's hbuf64 overlays this (dead by k3)
// e     :    65536
// inv   :   131072
// M     :   196608  (B*T*D   = 2097152)
// (gates buffer no longer needed: k4 fused into k5)

// ============================================================
// K1: s[b,t,r] = tanh(x[b,t,:] @ w1 + b1) @ w2 + b2
// ============================================================
__global__ __launch_bounds__(256) void k1_score(
    const float* __restrict__ x, const float* __restrict__ w1,
    const float* __restrict__ b1, const float* __restrict__ w2,
    const float* __restrict__ b2, float* __restrict__ s_out) {
  const int wave = threadIdx.x >> 6;
  const int lane = threadIdx.x & 63;
  for (int i = 0; i < 4; ++i) {
    const int bt = blockIdx.x * 16 + wave * 4 + i;  // grid=512 -> 8192 bt
    const float* xr = x + bt * DD;
    float acc = b1[lane];
    #pragma unroll 4
    for (int d = 0; d < DD; ++d)
      acc = fmaf(xr[d], w1[d * DA + lane], acc);   // w1 coalesced over lanes
    const float a = tanhf(acc);
    #pragma unroll
    for (int r = 0; r < RR; ++r) {
      float v = a * w2[lane * RR + r];
      for (int off = 32; off > 0; off >>= 1) v += __shfl_xor(v, off);
      if (lane == 0) s_out[bt * RR + r] = v + b2[r];
    }
  }
}

// ============================================================
// K2: per (b,r): m=max_t s; e=exp(s-m); den=inclusive prefix sum
// ============================================================
__global__ __launch_bounds__(512) void k2_prefix(
    const float* __restrict__ s_in, float* __restrict__ e_out,
    float* __restrict__ inv_out) {
  const int b = blockIdx.x >> 3, r = blockIdx.x & 7;
  const int t = threadIdx.x;
  __shared__ float red[TT];
  __shared__ float buf[2][TT];
  const float v = s_in[(b * TT + t) * RR + r];
  red[t] = v;
  __syncthreads();
  for (int off = 256; off >= 1; off >>= 1) {
    if (t < off) red[t] = fmaxf(red[t], red[t + off]);
    __syncthreads();
  }
  const float m = red[0];
  const float e = expf(v - m);
  int p = 0;
  buf[0][t] = e;
  __syncthreads();
  for (int off = 1; off < TT; off <<= 1) {
    const float add = (t >= off) ? buf[p][t - off] : 0.f;
    buf[1 - p][t] = buf[p][t] + add;
    __syncthreads();
    p ^= 1;
  }
  const float den = buf[p][t];
  e_out[(b * TT + t) * RR + r] = e;
  inv_out[(b * TT + t) * RR + r] = 1.0f / den;
}

// ============================================================
// K3: M[b,t,d] = (1/R) * sum_r inv[t,r] * prefix_j<=t( e[j,r]*x[b,j,d] )
// ============================================================
__global__ __launch_bounds__(64) void k3_mix(
    const float* __restrict__ x, const float* __restrict__ e_in,
    const float* __restrict__ inv_in, float* __restrict__ Mout) {
  const int b = blockIdx.x >> 2;
  const int d = (blockIdx.x & 3) * 64 + threadIdx.x;
  __shared__ __align__(16) float el[TT * RR];
  __shared__ __align__(16) float il[TT * RR];
  for (int i = threadIdx.x * 4; i < TT * RR; i += 64 * 4) {
    *(float4*)&el[i] = *(const float4*)&e_in[b * TT * RR + i];
    *(float4*)&il[i] = *(const float4*)&inv_in[b * TT * RR + i];
  }
  __syncthreads();
  float4 c0 = {0.f, 0.f, 0.f, 0.f}, c1 = {0.f, 0.f, 0.f, 0.f};
  for (int t = 0; t < TT; ++t) {
    const float xv = x[(b * TT + t) * DD + d];
    const float4 e0 = *(const float4*)&el[t * RR];
    const float4 e1 = *(const float4*)&el[t * RR + 4];
    const float4 i0 = *(const float4*)&il[t * RR];
    const float4 i1 = *(const float4*)&il[t * RR + 4];
    c0.x = fmaf(e0.x, xv, c0.x); c0.y = fmaf(e0.y, xv, c0.y);
    c0.z = fmaf(e0.z, xv, c0.z); c0.w = fmaf(e0.w, xv, c0.w);
    c1.x = fmaf(e1.x, xv, c1.x); c1.y = fmaf(e1.y, xv, c1.y);
    c1.z = fmaf(e1.z, xv, c1.z); c1.w = fmaf(e1.w, xv, c1.w);
    float msum = c0.x * i0.x + c0.y * i0.y + c0.z * i0.z + c0.w * i0.w;
    msum += c1.x * i1.x + c1.y * i1.y + c1.z * i1.z + c1.w * i1.w;
    Mout[(b * TT + t) * DD + d] = msum * 0.125f;
  }
}

#define FMA4(ACC, W4, HSC)                         \
  ACC.x = fmaf((W4).x, (HSC), ACC.x);              \
  ACC.y = fmaf((W4).y, (HSC), ACC.y);              \
  ACC.z = fmaf((W4).z, (HSC), ACC.z);              \
  ACC.w = fmaf((W4).w, (HSC), ACC.w);

// fast transcendentals: v_exp_f32 + v_rcp_f32 (~1e-6 err << 1.5e-2 tol)
__device__ __forceinline__ float fast_sigmoid(float x) {
  return __builtin_amdgcn_rcpf(1.f + __expf(-x));
}
__device__ __forceinline__ float fast_tanh(float x) {
  const float xc = fmaxf(x, -30.f);           // avoid inf*0 NaN
  const float e = __expf(-2.f * xc);
  return (1.f - e) * __builtin_amdgcn_rcpf(1.f + e);
}

#define HPOLL(Q) __hip_atomic_load((Q), __ATOMIC_RELAXED, __HIP_MEMORY_SCOPE_AGENT)

// ============================================================
// K5 v12: v11 (k4 fused, 933us) + two fixes from R4 counters:
//  (1) POLL-FIRST pipeline: v11's pin forced FMA-x BEFORE the poll
//      sample -> +160cy/step fully serial (933 vs v7's 899). Now
//      sample-0 (HPOLL) is issued FIRST, FMA-x runs inside its ~RT
//      flight, tag check + retry loop after. Volatile-order chain
//      (atomic -> sched_barrier -> ds_reads -> pin asm -> atomic loop)
//      stops the compiler from re-serializing either way.
//  (2) CONFLICT-FREE W_ih layout: v11's [kq][dim][cq] stride-2052
//      layout cost 4.1 extra cycles per ds_read_b128 (SQ_LDS_BANK_
//      CONFLICT 7.3M -> 76.3M). New layout stores the float4 of
//      (dim kq*16+i, unit cq) at word (cq>>2)*4096 + i*256 +
//      ((cq&3)*16+kq)*4: each wave's 64 lanes read ONE CONTIGUOUS
//      1KB block per instruction (lane l -> bytes l*16..l*16+15) ->
//      zero bank conflicts under any phase model.
// Exchange protocol unchanged (v7, proven): tag >= t self-validating
// packets, parity slots, ONE barrier/step. memset stays: stale slots
// from the PREVIOUS rep hold exactly tag t (same-step leftovers), so
// unpoisoned tags would accept stale h.
// ============================================================
__global__ __launch_bounds__(512, 1) void k5_lstm(
    const float* __restrict__ Mrow, const float* __restrict__ whh,
    const float* __restrict__ wih, const float* __restrict__ bias,
    float* __restrict__ out, unsigned long long* hbuf) {
  const int s   = blockIdx.x & 15;       // unit-slice
  const int b   = blockIdx.x >> 4;       // batch = sync domain
  const int tid = threadIdx.x;           // 512 threads
  const int kq  = tid & 15;              // k-chunk: k in [kq*32, kq*32+32)
  const int cq  = tid >> 4;              // unit offset 0..31
  const int j0  = s * 32;
  const int unit = j0 + cq;

  __shared__ __align__(16) float Wl[32768];       // 128 KB (staging + W_ih)
  __shared__ __align__(16) float hl[2][576];      // parity; chunk*36+pos
  __shared__ __align__(16) float M_lds[2][320];   // stride-20 per 16 dims

  // ---- rounds 0-1: stage whh slice, gather wr into registers (= v7) ----
  // wr[kk] = (W[k][i-col], W[k][f-col], W[k][g-col], W[k][o-col]) of
  // THIS thread's unit, k = (kq&7)*32 + kk + 256*(kq>>3)-round.
  float4 wr[32];
  for (int rnd = 0; rnd < 2; ++rnd) {
    for (int i = tid * 4; i < 256 * 128; i += 512 * 4) {
      const int k = i >> 7, c = i & 127;   // Wl[k][c], c = gate*32 + uo
      *(float4*)&Wl[i] =
          *(const float4*)&whh[(rnd * 256 + k) * G4H + (c >> 5) * HS + j0 + (c & 31)];
    }
    __syncthreads();
    if ((kq >> 3) == rnd) {
      const int kb = (kq & 7) * 32;
      #pragma unroll
      for (int kk = 0; kk < 32; ++kk) {
        const int base = (kb + kk) * 128 + cq;
        wr[kk].x = *(volatile const float*)&Wl[base];
        wr[kk].y = *(volatile const float*)&Wl[base + 32];
        wr[kk].z = *(volatile const float*)&Wl[base + 64];
        wr[kk].w = *(volatile const float*)&Wl[base + 96];
      }
    }
    __syncthreads();
  }

  // ---- round 2: stage W_ih slice, WAVE-CONTIGUOUS layout ----
  // word(wv,i,l) = wv*4096 + i*256 + l*4 holds the 4 gate columns of
  // unit j0 + (wv*4 + (l>>4)) at input dim (l&15)*16 + i. Reader wave
  // wv then reads 1KB contiguous per (wv,i) -> conflict-free.
  for (int m = tid * 4; m < 32768; m += 512 * 4) {
    const int wv = m >> 12;            // 0..7
    const int ii = (m >> 8) & 15;      // 0..15
    const int l  = (m >> 2) & 63;      // 0..63
    const int g_kq = l & 15, g_cq = wv * 4 + (l >> 4);
    const int row = g_kq * 16 + ii;    // input dim
    float4 w4;
    w4.x = wih[row * G4H + 0 * HS + j0 + g_cq];
    w4.y = wih[row * G4H + 1 * HS + j0 + g_cq];
    w4.z = wih[row * G4H + 2 * HS + j0 + g_cq];
    w4.w = wih[row * G4H + 3 * HS + j0 + g_cq];
    *(float4*)&Wl[m] = w4;
  }
  // M row 0 into parity buffer 0 (dim d lives at word (d>>4)*20 + (d&15))
  if (tid < 64)
    *(float4*)&M_lds[0][(tid >> 2) * 20 + (tid & 3) * 4] =
        *(const float4*)&Mrow[(long)b * TT * DD + tid * 4];
  // bias preload (epilogue lanes only)
  float bi = 0.f, bf = 0.f, bg = 0.f, bo = 0.f;
  if (kq == 0) {
    bi = bias[unit];          bf = bias[HS + unit];
    bg = bias[2 * HS + unit]; bo = bias[3 * HS + unit];
  }
  __syncthreads();

  float c_reg = 0.f;   // cell state (lives in lanes kq==0; unit j0+cq)

  for (int t = 0; t < TT; ++t) {
    const int par = t & 1;
    // prefetch M row t+1 (64 threads, one float4 each; lands during step)
    float4 mnext = {0.f, 0.f, 0.f, 0.f};
    if (tid < 64) {
      const int tn = (t + 1 < TT) ? t + 1 : t;   // clamp (last write unused)
      mnext = *(const float4*)&Mrow[((long)b * TT + tn) * DD + tid * 4];
    }
    // POLL-FIRST: sample 0 issued before FMA-x; its ~RT flight covers
    // the whole FMA-x phase. Check + retry after.
    const unsigned long long* hsrc =
        hbuf + (((t - 1) & 1) * BB + b) * HS + tid;
    unsigned long long pkt = 0;
    if (t > 0) pkt = HPOLL(hsrc);
    __builtin_amdgcn_sched_barrier(0);   // keep sample-0 above the ds_reads
    // FMA-x: acc = W_ih partial over input dims [kq*16, kq*16+16).
    float4 acc = {0.f, 0.f, 0.f, 0.f};
    {
      const float* Lp = &Wl[(cq >> 2) * 4096 + ((cq & 3) * 16 + kq) * 4];
      const float* mp = &M_lds[par][kq * 20];
      #pragma unroll
      for (int i = 0; i < 16; ++i) {
        const float4 w4 = *(const float4*)(Lp + i * 256);
        const float mv = mp[i];
        FMA4(acc, w4, mv);
      }
    }
    // pin acc here: FMA-x cannot sink past the retry loop / barrier
    asm volatile("" : "+v"(acc.x), "+v"(acc.y), "+v"(acc.z), "+v"(acc.w));
    if (t > 0) {
      // self-validating retry poll (tag >= t) -- v7 protocol
      while ((unsigned)(pkt >> 32) < (unsigned)t) pkt = HPOLL(hsrc);
      hl[par][(tid >> 5) * 36 + (tid & 31)] = __uint_as_float((unsigned)pkt);
    }
    // publish M row t+1 for next step (readers are past the barrier)
    if (tid < 64)
      *(float4*)&M_lds[par ^ 1][(tid >> 2) * 20 + (tid & 3) * 4] = mnext;
    __syncthreads();  // the ONE barrier: hl[par] + M_lds[par^1] complete
    if (t > 0) {
      const float* hb = &hl[par][kq * 36];
      #pragma unroll
      for (int i = 0; i < 8; ++i) {
        const float4 h4 = *(const float4*)(hb + i * 4);
        FMA4(acc, wr[i * 4 + 0], h4.x);
        FMA4(acc, wr[i * 4 + 1], h4.y);
        FMA4(acc, wr[i * 4 + 2], h4.z);
        FMA4(acc, wr[i * 4 + 3], h4.w);
      }
    }
    // butterfly over the 16 kq lanes (in-wave: group = 16 consecutive)
    #pragma unroll
    for (int off = 1; off <= 8; off <<= 1) {
      acc.x += __shfl_xor(acc.x, off); acc.y += __shfl_xor(acc.y, off);
      acc.z += __shfl_xor(acc.z, off); acc.w += __shfl_xor(acc.w, off);
    }
    // fused epilogue + publish: lane kq==0 has full (i,f,g,o) of unit
    if (kq == 0) {
      const float I = fast_sigmoid(acc.x + bi);
      const float F = fast_sigmoid(acc.y + bf);
      const float G = fast_tanh(acc.z + bg);
      const float O = fast_sigmoid(acc.w + bo);
      c_reg = F * c_reg + I * G;
      const float h = O * fast_tanh(c_reg);
      const unsigned long long pkt2 =
          ((unsigned long long)(unsigned)(t + 1) << 32) |
          (unsigned long long)__float_as_uint(h);
      __hip_atomic_store(&hbuf[((t & 1) * BB + b) * HS + unit], pkt2,
                         __ATOMIC_RELAXED, __HIP_MEMORY_SCOPE_AGENT);
      out[((long)b * TT + t) * HS + unit] = h;   // hidden_seq (post-publish)
      if (t == TT - 1) {
        out[(long)BB * TT * HS + b * HS + unit] = h;               // h_t
        out[(long)BB * TT * HS + BB * HS + b * HS + unit] = c_reg; // c_t
      }
    }
  }
}

// ============================================================
extern "C" void kernel_launch(void* const* d_in, const int* in_sizes, int n_in,
                              void* d_out, int out_size, void* d_ws,
                              size_t ws_size, hipStream_t stream) {
  const float* x    = (const float*)d_in[0];
  const float* w1   = (const float*)d_in[1];
  const float* b1   = (const float*)d_in[2];
  const float* w2   = (const float*)d_in[3];
  const float* b2   = (const float*)d_in[4];
  const float* wih  = (const float*)d_in[5];
  const float* whh  = (const float*)d_in[6];
  const float* bias = (const float*)d_in[7];
  float* out = (float*)d_out;

  float* ws = (float*)d_ws;
  float* s_buf  = ws;                    // 65536 floats; dead after k2
  float* e_buf  = ws + 65536;
  float* i_buf  = ws + 131072;
  float* M_buf  = ws + 196608;
  // hbuf64 overlays the s region (2*16*512 uint64 = 128 KB <= 256 KB)
  unsigned long long* hbuf64 = (unsigned long long*)ws;

  k1_score<<<512, 256, 0, stream>>>(x, w1, b1, w2, b2, s_buf);
  k2_prefix<<<BB * RR, 512, 0, stream>>>(s_buf, e_buf, i_buf);
  k3_mix<<<64, 64, 0, stream>>>(x, e_buf, i_buf, M_buf);
  // zero the packet tags (ws re-poisoned 0xAA each call; 0xAAAAAAAA > any t
  // would instantly satisfy polls; and a stale same-step tag from the
  // previous rep would too). Stream-ordered after k2's s_buf reads.
  hipMemsetAsync(hbuf64, 0, 2 * BB * HS * sizeof(unsigned long long), stream);
  k5_lstm<<<256, 512, 0, stream>>>(M_buf, whh, wih, bias, out, hbuf64);
}

// Round 6
// 1085.029 us; speedup vs baseline: 1.1977x; 1.1977x over previous
//
#include <hip/hip_runtime.h>
#include <math.h>

// Problem constants (reference: B,T,D=16,512,256; HS=512, D_A=64, R=8)
#define BB 16
#define TT 512
#define DD 256
#define HS 512
#define DA 64
#define RR 8
#define G4H 2048   // 4*HS

// -------- workspace layout (float offsets) --------
// s     :        0  (B*T*R =  65536)  <- k5's hbuf64 overlays this (dead by k3)
// e     :    65536
// inv   :   131072
// M     :   196608  (B*T*D   = 2097152)
// (gates buffer no longer needed: k4 fused into k5)

// ============================================================
// K1: s[b,t,r] = tanh(x[b,t,:] @ w1 + b1) @ w2 + b2
// ============================================================
__global__ __launch_bounds__(256) void k1_score(
    const float* __restrict__ x, const float* __restrict__ w1,
    const float* __restrict__ b1, const float* __restrict__ w2,
    const float* __restrict__ b2, float* __restrict__ s_out) {
  const int wave = threadIdx.x >> 6;
  const int lane = threadIdx.x & 63;
  for (int i = 0; i < 4; ++i) {
    const int bt = blockIdx.x * 16 + wave * 4 + i;  // grid=512 -> 8192 bt
    const float* xr = x + bt * DD;
    float acc = b1[lane];
    #pragma unroll 4
    for (int d = 0; d < DD; ++d)
      acc = fmaf(xr[d], w1[d * DA + lane], acc);   // w1 coalesced over lanes
    const float a = tanhf(acc);
    #pragma unroll
    for (int r = 0; r < RR; ++r) {
      float v = a * w2[lane * RR + r];
      for (int off = 32; off > 0; off >>= 1) v += __shfl_xor(v, off);
      if (lane == 0) s_out[bt * RR + r] = v + b2[r];
    }
  }
}

// ============================================================
// K2: per (b,r): m=max_t s; e=exp(s-m); den=inclusive prefix sum
// ============================================================
__global__ __launch_bounds__(512) void k2_prefix(
    const float* __restrict__ s_in, float* __restrict__ e_out,
    float* __restrict__ inv_out) {
  const int b = blockIdx.x >> 3, r = blockIdx.x & 7;
  const int t = threadIdx.x;
  __shared__ float red[TT];
  __shared__ float buf[2][TT];
  const float v = s_in[(b * TT + t) * RR + r];
  red[t] = v;
  __syncthreads();
  for (int off = 256; off >= 1; off >>= 1) {
    if (t < off) red[t] = fmaxf(red[t], red[t + off]);
    __syncthreads();
  }
  const float m = red[0];
  const float e = expf(v - m);
  int p = 0;
  buf[0][t] = e;
  __syncthreads();
  for (int off = 1; off < TT; off <<= 1) {
    const float add = (t >= off) ? buf[p][t - off] : 0.f;
    buf[1 - p][t] = buf[p][t] + add;
    __syncthreads();
    p ^= 1;
  }
  const float den = buf[p][t];
  e_out[(b * TT + t) * RR + r] = e;
  inv_out[(b * TT + t) * RR + r] = 1.0f / den;
}

// ============================================================
// K3: M[b,t,d] = (1/R) * sum_r inv[t,r] * prefix_j<=t( e[j,r]*x[b,j,d] )
// ============================================================
__global__ __launch_bounds__(64) void k3_mix(
    const float* __restrict__ x, const float* __restrict__ e_in,
    const float* __restrict__ inv_in, float* __restrict__ Mout) {
  const int b = blockIdx.x >> 2;
  const int d = (blockIdx.x & 3) * 64 + threadIdx.x;
  __shared__ __align__(16) float el[TT * RR];
  __shared__ __align__(16) float il[TT * RR];
  for (int i = threadIdx.x * 4; i < TT * RR; i += 64 * 4) {
    *(float4*)&el[i] = *(const float4*)&e_in[b * TT * RR + i];
    *(float4*)&il[i] = *(const float4*)&inv_in[b * TT * RR + i];
  }
  __syncthreads();
  float4 c0 = {0.f, 0.f, 0.f, 0.f}, c1 = {0.f, 0.f, 0.f, 0.f};
  for (int t = 0; t < TT; ++t) {
    const float xv = x[(b * TT + t) * DD + d];
    const float4 e0 = *(const float4*)&el[t * RR];
    const float4 e1 = *(const float4*)&el[t * RR + 4];
    const float4 i0 = *(const float4*)&il[t * RR];
    const float4 i1 = *(const float4*)&il[t * RR + 4];
    c0.x = fmaf(e0.x, xv, c0.x); c0.y = fmaf(e0.y, xv, c0.y);
    c0.z = fmaf(e0.z, xv, c0.z); c0.w = fmaf(e0.w, xv, c0.w);
    c1.x = fmaf(e1.x, xv, c1.x); c1.y = fmaf(e1.y, xv, c1.y);
    c1.z = fmaf(e1.z, xv, c1.z); c1.w = fmaf(e1.w, xv, c1.w);
    float msum = c0.x * i0.x + c0.y * i0.y + c0.z * i0.z + c0.w * i0.w;
    msum += c1.x * i1.x + c1.y * i1.y + c1.z * i1.z + c1.w * i1.w;
    Mout[(b * TT + t) * DD + d] = msum * 0.125f;
  }
}

#define FMA4(ACC, W4, HSC)                         \
  ACC.x = fmaf((W4).x, (HSC), ACC.x);              \
  ACC.y = fmaf((W4).y, (HSC), ACC.y);              \
  ACC.z = fmaf((W4).z, (HSC), ACC.z);              \
  ACC.w = fmaf((W4).w, (HSC), ACC.w);

// fast transcendentals: v_exp_f32 + v_rcp_f32 (~1e-6 err << 1.5e-2 tol)
__device__ __forceinline__ float fast_sigmoid(float x) {
  return __builtin_amdgcn_rcpf(1.f + __expf(-x));
}
__device__ __forceinline__ float fast_tanh(float x) {
  const float xc = fmaxf(x, -30.f);           // avoid inf*0 NaN
  const float e = __expf(-2.f * xc);
  return (1.f - e) * __builtin_amdgcn_rcpf(1.f + e);
}

#define HPOLL(Q) __hip_atomic_load((Q), __ATOMIC_RELAXED, __HIP_MEMORY_SCOPE_AGENT)

// ============================================================
// K5 v13 = v11 STRUCTURE (933us measured) + v12 W_ih LAYOUT (8.4M
// conflicts measured). R5 post-mortem: the two v12 changes separated
// cleanly -- layout fix verified by SQ_LDS_BANK_CONFLICT 76.3M->8.4M;
// poll-first + sched_barrier(0) regressed 933->1162us steady state
// (sample-0 issued at step top ALWAYS misses: producer publishes at
// its step end; and the full scheduling wall blocked M-prefetch/addr
// overlap) plus produced a 33ms outlier dispatch (congestion snowball).
// Poll-first REVERTED; v11's order (FMA-x -> pin -> poll) restored.
// In v11 the FMA-x ds_reads sit on the serial chain, so the ~4 extra
// conflict-cycles per b128 read were real serial time: expect the
// clean layout to cut ~500 cyc/step off v11's critical path.
// Exchange protocol unchanged (v7, proven): tag >= t self-validating
// packets, parity slots, ONE barrier/step. memset stays: stale slots
// from the PREVIOUS rep hold exactly tag t (same-step leftovers), so
// unpoisoned tags would accept stale h.
// ============================================================
__global__ __launch_bounds__(512, 1) void k5_lstm(
    const float* __restrict__ Mrow, const float* __restrict__ whh,
    const float* __restrict__ wih, const float* __restrict__ bias,
    float* __restrict__ out, unsigned long long* hbuf) {
  const int s   = blockIdx.x & 15;       // unit-slice
  const int b   = blockIdx.x >> 4;       // batch = sync domain
  const int tid = threadIdx.x;           // 512 threads
  const int kq  = tid & 15;              // k-chunk: k in [kq*32, kq*32+32)
  const int cq  = tid >> 4;              // unit offset 0..31
  const int j0  = s * 32;
  const int unit = j0 + cq;

  __shared__ __align__(16) float Wl[32768];       // 128 KB (staging + W_ih)
  __shared__ __align__(16) float hl[2][576];      // parity; chunk*36+pos
  __shared__ __align__(16) float M_lds[2][320];   // stride-20 per 16 dims

  // ---- rounds 0-1: stage whh slice, gather wr into registers (= v7) ----
  // wr[kk] = (W[k][i-col], W[k][f-col], W[k][g-col], W[k][o-col]) of
  // THIS thread's unit, k = (kq&7)*32 + kk + 256*(kq>>3)-round.
  float4 wr[32];
  for (int rnd = 0; rnd < 2; ++rnd) {
    for (int i = tid * 4; i < 256 * 128; i += 512 * 4) {
      const int k = i >> 7, c = i & 127;   // Wl[k][c], c = gate*32 + uo
      *(float4*)&Wl[i] =
          *(const float4*)&whh[(rnd * 256 + k) * G4H + (c >> 5) * HS + j0 + (c & 31)];
    }
    __syncthreads();
    if ((kq >> 3) == rnd) {
      const int kb = (kq & 7) * 32;
      #pragma unroll
      for (int kk = 0; kk < 32; ++kk) {
        const int base = (kb + kk) * 128 + cq;
        wr[kk].x = *(volatile const float*)&Wl[base];
        wr[kk].y = *(volatile const float*)&Wl[base + 32];
        wr[kk].z = *(volatile const float*)&Wl[base + 64];
        wr[kk].w = *(volatile const float*)&Wl[base + 96];
      }
    }
    __syncthreads();
  }

  // ---- round 2: stage W_ih slice, WAVE-CONTIGUOUS layout (v12) ----
  // word(wv,i,l) = wv*4096 + i*256 + l*4 holds the 4 gate columns of
  // unit j0 + (wv*4 + (l>>4)) at input dim (l&15)*16 + i. Reader wave
  // wv then reads 1KB contiguous per (wv,i) -> conflict-free.
  for (int m = tid * 4; m < 32768; m += 512 * 4) {
    const int wv = m >> 12;            // 0..7
    const int ii = (m >> 8) & 15;      // 0..15
    const int l  = (m >> 2) & 63;      // 0..63
    const int g_kq = l & 15, g_cq = wv * 4 + (l >> 4);
    const int row = g_kq * 16 + ii;    // input dim
    float4 w4;
    w4.x = wih[row * G4H + 0 * HS + j0 + g_cq];
    w4.y = wih[row * G4H + 1 * HS + j0 + g_cq];
    w4.z = wih[row * G4H + 2 * HS + j0 + g_cq];
    w4.w = wih[row * G4H + 3 * HS + j0 + g_cq];
    *(float4*)&Wl[m] = w4;
  }
  // M row 0 into parity buffer 0 (dim d lives at word (d>>4)*20 + (d&15))
  if (tid < 64)
    *(float4*)&M_lds[0][(tid >> 2) * 20 + (tid & 3) * 4] =
        *(const float4*)&Mrow[(long)b * TT * DD + tid * 4];
  // bias preload (epilogue lanes only)
  float bi = 0.f, bf = 0.f, bg = 0.f, bo = 0.f;
  if (kq == 0) {
    bi = bias[unit];          bf = bias[HS + unit];
    bg = bias[2 * HS + unit]; bo = bias[3 * HS + unit];
  }
  __syncthreads();

  float c_reg = 0.f;   // cell state (lives in lanes kq==0; unit j0+cq)

  for (int t = 0; t < TT; ++t) {
    const int par = t & 1;
    // prefetch M row t+1 (64 threads, one float4 each; lands during step)
    float4 mnext = {0.f, 0.f, 0.f, 0.f};
    if (tid < 64) {
      const int tn = (t + 1 < TT) ? t + 1 : t;   // clamp (last write unused)
      mnext = *(const float4*)&Mrow[((long)b * TT + tn) * DD + tid * 4];
    }
    // FMA-x: acc = W_ih partial over input dims [kq*16, kq*16+16).
    // (v11 order: FMA-x first, then pin, then poll.)
    float4 acc = {0.f, 0.f, 0.f, 0.f};
    {
      const float* Lp = &Wl[(cq >> 2) * 4096 + ((cq & 3) * 16 + kq) * 4];
      const float* mp = &M_lds[par][kq * 20];
      #pragma unroll
      for (int i = 0; i < 16; ++i) {
        const float4 w4 = *(const float4*)(Lp + i * 256);
        const float mv = mp[i];
        FMA4(acc, w4, mv);
      }
    }
    // pin: keep FMA-x scheduled before the poll loop (cheap, once/step)
    asm volatile("" : "+v"(acc.x), "+v"(acc.y), "+v"(acc.z), "+v"(acc.w));
    if (t > 0) {
      // self-validating poll of my own unit's packet (tag >= t) -- v7
      const unsigned long long* hsrc =
          hbuf + (((t - 1) & 1) * BB + b) * HS + tid;
      unsigned long long pkt;
      do { pkt = HPOLL(hsrc); } while ((unsigned)(pkt >> 32) < (unsigned)t);
      hl[par][(tid >> 5) * 36 + (tid & 31)] = __uint_as_float((unsigned)pkt);
    }
    // publish M row t+1 for next step (readers are past the barrier)
    if (tid < 64)
      *(float4*)&M_lds[par ^ 1][(tid >> 2) * 20 + (tid & 3) * 4] = mnext;
    __syncthreads();  // the ONE barrier: hl[par] + M_lds[par^1] complete
    if (t > 0) {
      const float* hb = &hl[par][kq * 36];
      #pragma unroll
      for (int i = 0; i < 8; ++i) {
        const float4 h4 = *(const float4*)(hb + i * 4);
        FMA4(acc, wr[i * 4 + 0], h4.x);
        FMA4(acc, wr[i * 4 + 1], h4.y);
        FMA4(acc, wr[i * 4 + 2], h4.z);
        FMA4(acc, wr[i * 4 + 3], h4.w);
      }
    }
    // butterfly over the 16 kq lanes (in-wave: group = 16 consecutive)
    #pragma unroll
    for (int off = 1; off <= 8; off <<= 1) {
      acc.x += __shfl_xor(acc.x, off); acc.y += __shfl_xor(acc.y, off);
      acc.z += __shfl_xor(acc.z, off); acc.w += __shfl_xor(acc.w, off);
    }
    // fused epilogue + publish: lane kq==0 has full (i,f,g,o) of unit
    if (kq == 0) {
      const float I = fast_sigmoid(acc.x + bi);
      const float F = fast_sigmoid(acc.y + bf);
      const float G = fast_tanh(acc.z + bg);
      const float O = fast_sigmoid(acc.w + bo);
      c_reg = F * c_reg + I * G;
      const float h = O * fast_tanh(c_reg);
      const unsigned long long pkt2 =
          ((unsigned long long)(unsigned)(t + 1) << 32) |
          (unsigned long long)__float_as_uint(h);
      __hip_atomic_store(&hbuf[((t & 1) * BB + b) * HS + unit], pkt2,
                         __ATOMIC_RELAXED, __HIP_MEMORY_SCOPE_AGENT);
      out[((long)b * TT + t) * HS + unit] = h;   // hidden_seq (post-publish)
      if (t == TT - 1) {
        out[(long)BB * TT * HS + b * HS + unit] = h;               // h_t
        out[(long)BB * TT * HS + BB * HS + b * HS + unit] = c_reg; // c_t
      }
    }
  }
}

// ============================================================
extern "C" void kernel_launch(void* const* d_in, const int* in_sizes, int n_in,
                              void* d_out, int out_size, void* d_ws,
                              size_t ws_size, hipStream_t stream) {
  const float* x    = (const float*)d_in[0];
  const float* w1   = (const float*)d_in[1];
  const float* b1   = (const float*)d_in[2];
  const float* w2   = (const float*)d_in[3];
  const float* b2   = (const float*)d_in[4];
  const float* wih  = (const float*)d_in[5];
  const float* whh  = (const float*)d_in[6];
  const float* bias = (const float*)d_in[7];
  float* out = (float*)d_out;

  float* ws = (float*)d_ws;
  float* s_buf  = ws;                    // 65536 floats; dead after k2
  float* e_buf  = ws + 65536;
  float* i_buf  = ws + 131072;
  float* M_buf  = ws + 196608;
  // hbuf64 overlays the s region (2*16*512 uint64 = 128 KB <= 256 KB)
  unsigned long long* hbuf64 = (unsigned long long*)ws;

  k1_score<<<512, 256, 0, stream>>>(x, w1, b1, w2, b2, s_buf);
  k2_prefix<<<BB * RR, 512, 0, stream>>>(s_buf, e_buf, i_buf);
  k3_mix<<<64, 64, 0, stream>>>(x, e_buf, i_buf, M_buf);
  // zero the packet tags (ws re-poisoned 0xAA each call; 0xAAAAAAAA > any t
  // would instantly satisfy polls; and a stale same-step tag from the
  // previous rep would too). Stream-ordered after k2's s_buf reads.
  hipMemsetAsync(hbuf64, 0, 2 * BB * HS * sizeof(unsigned long long), stream);
  k5_lstm<<<256, 512, 0, stream>>>(M_buf, whh, wih, bias, out, hbuf64);
}